// Round 5
// baseline (674.180 us; speedup 1.0000x reference)
//
#include <hip/hip_runtime.h>
#include <hip/hip_bf16.h>

// Round 5: barrier-free 1-wave 64x64 GEMM (3-buffer, counted vmcnt, no s_barrier),
// everything else carried from R4 (no-max fused attention, consolidated repack).

constexpr int S_ = 2048;
constexpr int E_ = 1024;
constexpr int H_ = 16;
constexpr int HS_ = 64;
constexpr int L_ = 2;
constexpr int FF_ = 4096;

typedef __bf16 bf16;
typedef __bf16 bf16x8 __attribute__((ext_vector_type(8)));
typedef __bf16 bf16x4 __attribute__((ext_vector_type(4)));
typedef float f32x4 __attribute__((ext_vector_type(4)));

__device__ __forceinline__ void gld16(const void* g, const void* l) {
  __builtin_amdgcn_global_load_lds(
      (const __attribute__((address_space(1))) unsigned int*)g,
      (__attribute__((address_space(3))) unsigned int*)l, 16, 0, 0);
}

// ---------------- embedding + first layernorm fused ----------------
__global__ __launch_bounds__(256) void embed_ln_k(const int* __restrict__ seq,
                                                  const float* __restrict__ tok,
                                                  const float* __restrict__ pos,
                                                  const float* __restrict__ gw,
                                                  const float* __restrict__ bw,
                                                  float* __restrict__ x,
                                                  bf16* __restrict__ xb) {
  __shared__ float red[8];
  const int row = blockIdx.x, tid = threadIdx.x;
  const int t = seq[row];
  float4 v = ((const float4*)(tok + (long)t * E_))[tid];
  float4 p = ((const float4*)(pos + (long)row * E_))[tid];
  v.x += p.x; v.y += p.y; v.z += p.z; v.w += p.w;
  float s = v.x + v.y + v.z + v.w;
  float ss = v.x * v.x + v.y * v.y + v.z * v.z + v.w * v.w;
  for (int off = 32; off; off >>= 1) {
    s += __shfl_down(s, off);
    ss += __shfl_down(ss, off);
  }
  if ((tid & 63) == 0) { red[(tid >> 6) * 2] = s; red[(tid >> 6) * 2 + 1] = ss; }
  __syncthreads();
  if (tid == 0) {
    float S0 = 0, SS = 0;
    for (int i = 0; i < 4; ++i) { S0 += red[i * 2]; SS += red[i * 2 + 1]; }
    red[0] = S0; red[1] = SS;
  }
  __syncthreads();
  const float mu = red[0] * (1.f / E_);
  const float var = red[1] * (1.f / E_) - mu * mu;
  const float rs = rsqrtf(var + 1e-5f);
  float4 gv = ((const float4*)gw)[tid], bv = ((const float4*)bw)[tid];
  float4 o;
  o.x = (v.x - mu) * rs * gv.x + bv.x;
  o.y = (v.y - mu) * rs * gv.y + bv.y;
  o.z = (v.z - mu) * rs * gv.z + bv.z;
  o.w = (v.w - mu) * rs * gv.w + bv.w;
  ((float4*)(x + (long)row * E_))[tid] = o;
  bf16x4 ob;
  ob[0] = (__bf16)o.x; ob[1] = (__bf16)o.y; ob[2] = (__bf16)o.z; ob[3] = (__bf16)o.w;
  ((bf16x4*)(xb + (long)row * E_))[tid] = ob;
}

// ---------------- layernorm (in-place f32) + bf16 shadow ----------------
__global__ __launch_bounds__(256) void layernorm_k(float* __restrict__ x,
                                                   const float* __restrict__ gw,
                                                   const float* __restrict__ bw,
                                                   bf16* __restrict__ xb) {
  __shared__ float red[8];
  const int row = blockIdx.x, tid = threadIdx.x;
  float4 v = ((const float4*)(x + (long)row * E_))[tid];
  float s = v.x + v.y + v.z + v.w;
  float ss = v.x * v.x + v.y * v.y + v.z * v.z + v.w * v.w;
  for (int off = 32; off; off >>= 1) {
    s += __shfl_down(s, off);
    ss += __shfl_down(ss, off);
  }
  if ((tid & 63) == 0) { red[(tid >> 6) * 2] = s; red[(tid >> 6) * 2 + 1] = ss; }
  __syncthreads();
  if (tid == 0) {
    float S0 = 0, SS = 0;
    for (int i = 0; i < 4; ++i) { S0 += red[i * 2]; SS += red[i * 2 + 1]; }
    red[0] = S0; red[1] = SS;
  }
  __syncthreads();
  const float mu = red[0] * (1.f / E_);
  const float var = red[1] * (1.f / E_) - mu * mu;
  const float rs = rsqrtf(var + 1e-5f);
  float4 gv = ((const float4*)gw)[tid], bv = ((const float4*)bw)[tid];
  float4 o;
  o.x = (v.x - mu) * rs * gv.x + bv.x;
  o.y = (v.y - mu) * rs * gv.y + bv.y;
  o.z = (v.z - mu) * rs * gv.z + bv.z;
  o.w = (v.w - mu) * rs * gv.w + bv.w;
  ((float4*)(x + (long)row * E_))[tid] = o;
  bf16x4 ob;
  ob[0] = (__bf16)o.x; ob[1] = (__bf16)o.y; ob[2] = (__bf16)o.z; ob[3] = (__bf16)o.w;
  ((bf16x4*)(xb + (long)row * E_))[tid] = ob;
}

// ---------------- unified weight repack for one layer ----------------
__global__ __launch_bounds__(256) void repack_k(const float* __restrict__ wq,
                                                const float* __restrict__ wk,
                                                const float* __restrict__ wv,
                                                const float* __restrict__ wr,
                                                const float* __restrict__ w1,
                                                const float* __restrict__ w2,
                                                bf16* __restrict__ qkvT,
                                                bf16* __restrict__ wrT,
                                                bf16* __restrict__ w1T,
                                                bf16* __restrict__ w2T) {
  __shared__ float t[32][33];
  const int tx = threadIdx.x, ty = threadIdx.y;
  const int bid = blockIdx.x;
  const float* src;
  bf16* dst;
  long ld_in, ld_out, r0, c0;
  if (bid < 3072) {
    const int j = bid >> 10;
    const int z = (bid & 1023) >> 6;
    const int rem = bid & 63;
    r0 = (rem >> 1) * 32;
    c0 = (rem & 1) * 32;
    const float* w = j == 0 ? wq : (j == 1 ? wk : wv);
    src = w + (long)z * E_ * HS_;
    dst = qkvT + (long)j * E_ * E_ + (long)z * HS_ * E_;
    ld_in = HS_; ld_out = E_;
  } else if (bid < 4096) {
    const int idx = bid - 3072;
    r0 = (idx >> 5) * 32; c0 = (idx & 31) * 32;
    src = wr; dst = wrT; ld_in = E_; ld_out = E_;
  } else if (bid < 8192) {
    const int idx = bid - 4096;
    r0 = (idx >> 7) * 32; c0 = (idx & 127) * 32;
    src = w1; dst = w1T; ld_in = FF_; ld_out = E_;
  } else {
    const int idx = bid - 8192;
    r0 = (idx >> 5) * 32; c0 = (idx & 31) * 32;
    src = w2; dst = w2T; ld_in = E_; ld_out = FF_;
  }
#pragma unroll
  for (int i = 0; i < 4; ++i)
    t[ty + 8 * i][tx] = src[(r0 + ty + 8 * i) * ld_in + c0 + tx];
  __syncthreads();
#pragma unroll
  for (int i = 0; i < 4; ++i)
    dst[(c0 + ty + 8 * i) * ld_out + r0 + tx] = (__bf16)t[tx][ty + 8 * i];
}

// ---------------- bf16 transpose for V^T ----------------
__global__ __launch_bounds__(256) void trans_b2b(const bf16* __restrict__ in,
                                                 bf16* __restrict__ out,
                                                 long ld_in, long ld_out) {
  __shared__ bf16 t[32][33];
  const int tx = threadIdx.x, ty = threadIdx.y;
  const long r0 = (long)blockIdx.x * 32, c0 = (long)blockIdx.y * 32;
#pragma unroll
  for (int i = 0; i < 4; ++i)
    t[ty + 8 * i][tx] = in[(r0 + ty + 8 * i) * ld_in + c0 + tx];
  __syncthreads();
#pragma unroll
  for (int i = 0; i < 4; ++i)
    out[(c0 + ty + 8 * i) * ld_out + r0 + tx] = t[tx][ty + 8 * i];
}

// ---------------- barrier-free 1-wave 64x64 NT GEMM ----------------
// C[M,N] = scale*A[M,K]@B[N,K]^T (+bias +relu +resid). One wave per tile.
// 3 LDS buffers (A 4KB + B 4KB each); stage tile t+2, counted vmcnt orders
// staging vs ds_read with NO barrier (the wave issued its own loads).
__global__ __launch_bounds__(64) void gemm_w64(
    const bf16* __restrict__ A, const bf16* __restrict__ B,
    long lda, long ldb, int K, int mtiles, float scale,
    const float* __restrict__ bias, const float* __restrict__ resid, int relu,
    float* __restrict__ Cf, long ldc, bf16* __restrict__ Cb, long ldcb) {
  constexpr int ABY = 4096;   // 64 rows * 64 bytes
  constexpr int BUFB = 8192;  // A + B
  __shared__ char smem[3 * BUFB];

  const int lane = threadIdx.x;
  // XCD-chunked swizzle (grid % 8 == 0)
  const int cpx = gridDim.x >> 3;
  const int bid = blockIdx.x;
  const int wg = (bid & 7) * cpx + (bid >> 3);
  const long m0 = (long)(wg % mtiles) * 64;
  const long n0 = (long)(wg / mtiles) * 64;

  // staging descriptors: 8 chunks of 1KB (64 lanes x 16B)
  const char* gsrc[8];
  int ldsbase[8];
#pragma unroll
  for (int i = 0; i < 8; ++i) {
    const int s = i * 1024 + lane * 16;
    const bf16* base;
    int kb;
    if (s < ABY) {
      const int row = s >> 6;
      kb = (s ^ ((row & 3) << 4)) & 63;
      base = A + (m0 + row) * lda;
    } else {
      const int s2 = s - ABY;
      const int row = s2 >> 6;
      kb = (s2 ^ ((row & 3) << 4)) & 63;
      base = B + (n0 + row) * ldb;
    }
    gsrc[i] = (const char*)base + kb;
    ldsbase[i] = i * 1024;
  }

  const int fr = lane & 15, fg = lane >> 4;
  int aoff[4], boff[4];
#pragma unroll
  for (int t = 0; t < 4; ++t) {
    const int m = t * 16 + fr;
    aoff[t] = m * 64 + ((16 * fg) ^ ((m & 3) << 4));
    boff[t] = ABY + m * 64 + ((16 * fg) ^ ((m & 3) << 4));
  }

  f32x4 acc[4][4];
#pragma unroll
  for (int i = 0; i < 4; ++i)
#pragma unroll
    for (int j = 0; j < 4; ++j) acc[i][j] = (f32x4){0.f, 0.f, 0.f, 0.f};

  const int nt = K >> 5;

  auto stage = [&](int tile, int buf) {
    const long koff = (long)tile * 64;
#pragma unroll
    for (int i = 0; i < 8; ++i)
      gld16(gsrc[i] + koff, smem + buf * BUFB + ldsbase[i]);
  };

  stage(0, 0);
  stage(1, 1);

  int cur = 0;
  for (int t = 0; t < nt; ++t) {
    if (t + 2 < nt) {
      int sb = cur + 2; if (sb >= 3) sb -= 3;
      stage(t + 2, sb);
      asm volatile("s_waitcnt vmcnt(16)" ::: "memory");
    } else if (t + 1 < nt) {
      asm volatile("s_waitcnt vmcnt(8)" ::: "memory");
    } else {
      asm volatile("s_waitcnt vmcnt(0)" ::: "memory");
    }
    const char* sbuf = smem + cur * BUFB;
    bf16x8 a[4], b[4];
#pragma unroll
    for (int i = 0; i < 4; ++i) a[i] = *(const bf16x8*)(sbuf + aoff[i]);
#pragma unroll
    for (int i = 0; i < 4; ++i) b[i] = *(const bf16x8*)(sbuf + boff[i]);
#pragma unroll
    for (int i = 0; i < 4; ++i)
#pragma unroll
      for (int j = 0; j < 4; ++j)
        acc[i][j] = __builtin_amdgcn_mfma_f32_16x16x32_bf16(a[i], b[j], acc[i][j], 0, 0, 0);
    cur = cur + 1; if (cur >= 3) cur -= 3;
  }

#pragma unroll
  for (int tm = 0; tm < 4; ++tm) {
#pragma unroll
    for (int tn = 0; tn < 4; ++tn) {
      const long col = n0 + tn * 16 + fr;
#pragma unroll
      for (int i = 0; i < 4; ++i) {
        const long row = m0 + tm * 16 + fg * 4 + i;
        float v = acc[tm][tn][i] * scale;
        if (bias) v += bias[col];
        if (relu) v = v > 0.f ? v : 0.f;
        if (resid) v += resid[row * ldc + col];
        if (Cf) Cf[row * ldc + col] = v;
        if (Cb) Cb[row * ldcb + col] = (__bf16)v;
      }
    }
  }
}

// ---------------- fused two-pass attention (no-max softmax) ----------------
__global__ __launch_bounds__(256, 2) void attn_fused(
    const bf16* __restrict__ qkv,  // [S][3E]
    const bf16* __restrict__ vt,   // [E][S]
    float* __restrict__ att,       // [H][S][S]
    bf16* __restrict__ avb) {      // [S][E]
  constexpr int QB = 128, KB = 128;
  constexpr int NKT = S_ / KB;
  constexpr float C2 = 0.1803368801111244f;  // 0.125 * log2(e)
  __shared__ alignas(16) float plds[QB * KB];

  const int tid = threadIdx.x, lane = tid & 63, w = tid >> 6;
  const int fr = lane & 15, fg = lane >> 4;
  const int bid = blockIdx.x;
  const int wg = (bid & 7) * 32 + (bid >> 3);
  const int h = wg >> 4;
  const long q0 = (long)(wg & 15) * QB;
  const int qloc = w * 32;

  bf16x8 qf[2][2];
#pragma unroll
  for (int qnt = 0; qnt < 2; ++qnt)
#pragma unroll
    for (int k0 = 0; k0 < 2; ++k0)
      qf[qnt][k0] = *(const bf16x8*)(qkv + (q0 + qloc + qnt * 16 + fr) * (3 * E_) +
                                     h * HS_ + k0 * 32 + fg * 8);

  float l_[2] = {0.f, 0.f};

  // ---- pass 1 ----
  for (int kt = 0; kt < NKT; ++kt) {
    const long t0 = (long)kt * KB;
    bf16x8 kf[8][2];
#pragma unroll
    for (int mt = 0; mt < 8; ++mt)
#pragma unroll
      for (int k0 = 0; k0 < 2; ++k0)
        kf[mt][k0] = *(const bf16x8*)(qkv + (t0 + mt * 16 + fr) * (3 * E_) +
                                      E_ + h * HS_ + k0 * 32 + fg * 8);
    f32x4 acc[8][2];
#pragma unroll
    for (int mt = 0; mt < 8; ++mt)
#pragma unroll
      for (int qnt = 0; qnt < 2; ++qnt) acc[mt][qnt] = (f32x4){0.f, 0.f, 0.f, 0.f};
#pragma unroll
    for (int k0 = 0; k0 < 2; ++k0)
#pragma unroll
      for (int mt = 0; mt < 8; ++mt)
#pragma unroll
        for (int qnt = 0; qnt < 2; ++qnt)
          acc[mt][qnt] = __builtin_amdgcn_mfma_f32_16x16x32_bf16(kf[mt][k0], qf[qnt][k0], acc[mt][qnt], 0, 0, 0);
#pragma unroll
    for (int qnt = 0; qnt < 2; ++qnt) {
      float sum = 0.f;
#pragma unroll
      for (int mt = 0; mt < 8; ++mt)
#pragma unroll
        for (int i = 0; i < 4; ++i) sum += __builtin_amdgcn_exp2f(acc[mt][qnt][i] * C2);
      l_[qnt] += sum;
    }
  }
#pragma unroll
  for (int qnt = 0; qnt < 2; ++qnt) {
    l_[qnt] += __shfl_xor(l_[qnt], 16);
    l_[qnt] += __shfl_xor(l_[qnt], 32);
  }
  const float invl[2] = {1.f / l_[0], 1.f / l_[1]};

  f32x4 ao[4][2];
#pragma unroll
  for (int d = 0; d < 4; ++d)
#pragma unroll
    for (int q = 0; q < 2; ++q) ao[d][q] = (f32x4){0.f, 0.f, 0.f, 0.f};

  // ---- pass 2 ----
  for (int kt = 0; kt < NKT; ++kt) {
    const long t0 = (long)kt * KB;
    bf16x8 kf[8][2];
#pragma unroll
    for (int mt = 0; mt < 8; ++mt)
#pragma unroll
      for (int k0 = 0; k0 < 2; ++k0)
        kf[mt][k0] = *(const bf16x8*)(qkv + (t0 + mt * 16 + fr) * (3 * E_) +
                                      E_ + h * HS_ + k0 * 32 + fg * 8);
    f32x4 acc[8][2];
#pragma unroll
    for (int mt = 0; mt < 8; ++mt)
#pragma unroll
      for (int qnt = 0; qnt < 2; ++qnt) acc[mt][qnt] = (f32x4){0.f, 0.f, 0.f, 0.f};
#pragma unroll
    for (int k0 = 0; k0 < 2; ++k0)
#pragma unroll
      for (int mt = 0; mt < 8; ++mt)
#pragma unroll
        for (int qnt = 0; qnt < 2; ++qnt)
          acc[mt][qnt] = __builtin_amdgcn_mfma_f32_16x16x32_bf16(kf[mt][k0], qf[qnt][k0], acc[mt][qnt], 0, 0, 0);

#pragma unroll
    for (int qnt = 0; qnt < 2; ++qnt) {
      const int q = qloc + qnt * 16 + fr;
      const int swz = (q & 7) << 4;
#pragma unroll
      for (int mt = 0; mt < 8; ++mt) {
        f32x4 pv;
#pragma unroll
        for (int i = 0; i < 4; ++i)
          pv[i] = __builtin_amdgcn_exp2f(acc[mt][qnt][i] * C2) * invl[qnt];
        const int tb = (mt * 16 + fg * 4) * 4;
        *(f32x4*)((char*)plds + q * 512 + (tb ^ swz)) = pv;
      }
    }
    __syncthreads();

    {
      const int qq = tid >> 3, s8 = tid & 7;
#pragma unroll
      for (int rep = 0; rep < 4; ++rep) {
        const int q = qq + rep * 32;
        f32x4 v = *(const f32x4*)((char*)plds + q * 512 + ((s8 * 16) ^ ((q & 7) << 4)));
        __builtin_nontemporal_store(v, (f32x4*)(att + ((long)h * S_ + q0 + q) * S_ + t0 + s8 * 4));
      }
    }

#pragma unroll
    for (int k0 = 0; k0 < 4; ++k0) {
      bf16x8 bq[2];
#pragma unroll
      for (int qnt = 0; qnt < 2; ++qnt) {
        const int q = qloc + qnt * 16 + fr;
        const int swz = (q & 7) << 4;
        const int tb = k0 * 128 + fg * 32;
        f32x4 lo = *(const f32x4*)((char*)plds + q * 512 + (tb ^ swz));
        f32x4 hi = *(const f32x4*)((char*)plds + q * 512 + ((tb + 16) ^ swz));
        bf16x8 t;
#pragma unroll
        for (int j = 0; j < 4; ++j) { t[j] = (__bf16)lo[j]; t[4 + j] = (__bf16)hi[j]; }
        bq[qnt] = t;
      }
#pragma unroll
      for (int dmt = 0; dmt < 4; ++dmt) {
        bf16x8 av = *(const bf16x8*)(vt + (long)(h * HS_ + dmt * 16 + fr) * S_ +
                                     t0 + k0 * 32 + fg * 8);
#pragma unroll
        for (int qnt = 0; qnt < 2; ++qnt)
          ao[dmt][qnt] = __builtin_amdgcn_mfma_f32_16x16x32_bf16(av, bq[qnt], ao[dmt][qnt], 0, 0, 0);
      }
    }
    __syncthreads();
  }

  // O^T -> LDS -> avb
#pragma unroll
  for (int qnt = 0; qnt < 2; ++qnt) {
    const int q = qloc + qnt * 16 + fr;
    const int swz = (q & 7) << 4;
#pragma unroll
    for (int dmt = 0; dmt < 4; ++dmt) {
      const int db = (dmt * 16 + fg * 4) * 4;
      *(f32x4*)((char*)plds + q * 256 + (db ^ swz)) = ao[dmt][qnt];
    }
  }
  __syncthreads();
  {
    const int q = tid >> 1, half = tid & 1;
    const int swz = (q & 7) << 4;
    bf16* dst = avb + (q0 + q) * E_ + h * HS_ + half * 32;
#pragma unroll
    for (int j = 0; j < 8; ++j) {
      f32x4 v = *(const f32x4*)((char*)plds + q * 256 + ((half * 128 + j * 16) ^ swz));
      bf16x4 o;
      o[0] = (__bf16)v[0]; o[1] = (__bf16)v[1]; o[2] = (__bf16)v[2]; o[3] = (__bf16)v[3];
      *(bf16x4*)(dst + j * 4) = o;
    }
  }
}

extern "C" void kernel_launch(void* const* d_in, const int* in_sizes, int n_in,
                              void* d_out, int out_size, void* d_ws, size_t ws_size,
                              hipStream_t stream) {
  const int* seq = (const int*)d_in[0];
  const float* tok_emb = (const float*)d_in[1];
  const float* pos_emb = (const float*)d_in[2];
  const float* Wq = (const float*)d_in[3];
  const float* Wk = (const float*)d_in[4];
  const float* Wv = (const float*)d_in[5];
  const float* Wr = (const float*)d_in[6];
  const float* br = (const float*)d_in[7];
  const float* W1 = (const float*)d_in[8];
  const float* b1 = (const float*)d_in[9];
  const float* W2 = (const float*)d_in[10];
  const float* b2 = (const float*)d_in[11];
  const float* ln_g = (const float*)d_in[12];
  const float* ln_b = (const float*)d_in[13];

  float* outx = (float*)d_out;
  float* att_all = outx + (long)S_ * E_;

  char* w = (char*)d_ws;
  auto alloc = [&](size_t bytes) {
    char* p = w;
    w += (bytes + 255) & ~(size_t)255;
    return p;
  };
  float* x = (float*)alloc((size_t)S_ * E_ * 4);
  bf16* xb = (bf16*)alloc((size_t)S_ * E_ * 2);
  bf16* qkvb = (bf16*)alloc((size_t)S_ * 3 * E_ * 2);
  bf16* vt = (bf16*)alloc((size_t)E_ * S_ * 2);
  bf16* avb = (bf16*)alloc((size_t)S_ * E_ * 2);
  bf16* hb = (bf16*)alloc((size_t)S_ * FF_ * 2);
  bf16* wqkvT = (bf16*)alloc((size_t)3 * E_ * E_ * 2);
  bf16* wrT = (bf16*)alloc((size_t)E_ * E_ * 2);
  bf16* w1T = (bf16*)alloc((size_t)E_ * FF_ * 2);
  bf16* w2T = (bf16*)alloc((size_t)E_ * FF_ * 2);
  (void)ws_size; (void)in_sizes; (void)n_in; (void)out_size;

  embed_ln_k<<<S_, 256, 0, stream>>>(seq, tok_emb, pos_emb, ln_g, ln_b, x, xb);

  for (int l = 0; l < L_; ++l) {
    repack_k<<<12288, dim3(32, 8, 1), 0, stream>>>(
        Wq + (long)l * H_ * E_ * HS_, Wk + (long)l * H_ * E_ * HS_,
        Wv + (long)l * H_ * E_ * HS_, Wr + (long)l * E_ * E_,
        W1 + (long)l * E_ * FF_, W2 + (long)l * FF_ * E_,
        wqkvT, wrT, w1T, w2T);

    if (l > 0)
      layernorm_k<<<S_, 256, 0, stream>>>(x, ln_g + (long)l * E_, ln_b + (long)l * E_, xb);

    // qkv = xb @ WqkvT^T   [S, 3E]
    gemm_w64<<<32 * 48, 64, 0, stream>>>(
        xb, wqkvT, E_, E_, E_, 32, 1.f, nullptr, nullptr, 0,
        nullptr, 0, qkvb, 3 * E_);

    trans_b2b<<<dim3(S_ / 32, E_ / 32, 1), dim3(32, 8, 1), 0, stream>>>(
        qkvb + 2 * E_, vt, 3 * E_, S_);

    float* att_l = att_all + (long)l * H_ * S_ * S_;
    attn_fused<<<256, 256, 0, stream>>>(qkvb, vt, att_l, avb);

    // x = x + avb @ WrT^T + br
    gemm_w64<<<32 * 16, 64, 0, stream>>>(
        avb, wrT, E_, E_, E_, 32, 1.f, br + (long)l * E_, x, 0,
        x, E_, nullptr, 0);

    layernorm_k<<<S_, 256, 0, stream>>>(x, ln_g + (long)l * E_, ln_b + (long)l * E_, xb);

    // hb = relu(xb @ W1T^T + b1)
    gemm_w64<<<32 * 64, 64, 0, stream>>>(
        xb, w1T, E_, E_, E_, 32, 1.f, b1 + (long)l * FF_, nullptr, 1,
        nullptr, 0, hb, FF_);

    // x = x + hb @ W2T^T + b2   (last layer -> d_out)
    float* xdst = (l == L_ - 1) ? outx : x;
    gemm_w64<<<32 * 16, 64, 0, stream>>>(
        hb, w2T, FF_, FF_, FF_, 32, 1.f, b2 + (long)l * E_, x, 0,
        xdst, E_, nullptr, 0);
  }
}